// Round 1
// baseline (196.263 us; speedup 1.0000x reference)
//
#include <hip/hip_runtime.h>
#include <stdint.h>
#include <math.h>

#define C_NUM 65536
#define NPT 24

static __host__ __device__ __forceinline__ void tf2x32(uint32_t k0, uint32_t k1,
                                                       uint32_t& x0, uint32_t& x1) {
  const uint32_t ks2 = k0 ^ k1 ^ 0x1BD11BDAu;
#define TF_R(r) { x0 += x1; x1 = (x1 << (r)) | (x1 >> (32 - (r))); x1 ^= x0; }
  x0 += k0; x1 += k1;
  TF_R(13) TF_R(15) TF_R(26) TF_R(6)
  x0 += k1;  x1 += ks2 + 1u;
  TF_R(17) TF_R(29) TF_R(16) TF_R(24)
  x0 += ks2; x1 += k0 + 2u;
  TF_R(13) TF_R(15) TF_R(26) TF_R(6)
  x0 += k0;  x1 += k1 + 3u;
  TF_R(17) TF_R(29) TF_R(16) TF_R(24)
  x0 += k1;  x1 += ks2 + 4u;
  TF_R(13) TF_R(15) TF_R(26) TF_R(6)
  x0 += ks2; x1 += k0 + 5u;
#undef TF_R
}

// f32 uniform [0,1): x64-OFF partitionable path (jax _threefry_random_bits_partitionable):
//   counters (hi=0, lo=idx); bits32 = out0 ^ out1; u = bitcast((bits>>9)|0x3f800000) - 1.0f
// (replaces prior f64 variant which matched only an x64-enabled reference)
__device__ __forceinline__ float jax_u01f(uint32_t ka, uint32_t kb, uint32_t idx) {
  uint32_t x0 = 0u, x1 = idx;
  tf2x32(ka, kb, x0, x1);
  const uint32_t bits = x0 ^ x1;
  return __fadd_rn(__uint_as_float((bits >> 9) | 0x3f800000u), -1.0f);
}

// XLA:CPU llvm_ir_runtime GenerateVF32Exp, bitwise replica (FMA-contracted, as LLVM
// emits under XLA fast-math on an FMA-capable x86 host).
__device__ __forceinline__ float xla_vf32_exp(float x) {
  float xc = fminf(x, 88.3762626647950f);     // exp_hi
  xc = fmaxf(xc, -87.3365478515625f);         // exp_lo
  const float fx = floorf(fmaf(xc, 1.44269504088896341f, 0.5f));
  float r = fmaf(fx, -0.693359375f, xc);      // cephes_exp_C1
  r = fmaf(fx, 2.12194440e-4f, r);            // -C2
  const float z = __fmul_rn(r, r);
  float y = 1.9875691500e-4f;                 // p0
  y = fmaf(y, r, 1.3981999507e-3f);           // p1
  y = fmaf(y, r, 8.3334519073e-3f);           // p2
  y = fmaf(y, r, 4.1665795894e-2f);           // p3
  y = fmaf(y, r, 1.6666665459e-1f);           // p4
  y = fmaf(y, r, 5.0000001201e-1f);           // p5
  y = fmaf(y, z, r);
  y = __fadd_rn(y, 1.0f);
  const int n = (int)fx;                      // our inputs: |fx| <= ~9, exact scale
  return __fmul_rn(y, __uint_as_float((uint32_t)(127 + n) << 23));
}

// exp(-a) with underflow shortcut; a >= 0 (smooth path, f64)
static __device__ __forceinline__ double gexp(double a) {
  return (a > 700.0) ? 0.0 : exp(-a);
}

// ---------------- Kernel A: per-row cols + weights -> table ----------------
// means: f32 exp-form logistic with XLA GenerateVF32Exp; smooth parts f64.
// Draws: f32 partitionable threefry (x64-off reference).
__global__ void __launch_bounds__(256) wkern(const float* __restrict__ params,
                                             int* __restrict__ tab,
                                             uint32_t kr0, uint32_t kr1,
                                             uint32_t kg0, uint32_t kg1) {
  const int row = blockIdx.x * 256 + threadIdx.x;
  if (row >= C_NUM) return;

  const float c1f = (float)(1.0 - 1e-6);  // f32(1.0 - EPSILON), same convert as XLA

  float m32[4];
  double means[4], sigv[4], valv[4];
#pragma unroll
  for (int kk = 0; kk < 4; ++kk) {
    const int r = row * 4 + kk;
    const float p0 = params[r * 3 + 0];
    const double p1 = (double)params[r * 3 + 1];
    const double p2 = (double)params[r * 3 + 2];
    // XLA logistic (exp-form): s = 1/(1 + exp(-x)); means = s * 65535  (all f32)
    const float e32 = xla_vf32_exp(-p0);
    const float s32 = __fdiv_rn(1.0f, __fadd_rn(1.0f, e32));
    m32[kk] = __fmul_rn(s32, 65535.0f);
    means[kk] = (double)m32[kk];
    const double xx = p1 + 2.0;
    const double sp = fmax(xx, 0.0) + log1p(exp(-fabs(xx)));  // softplus smooth -> f64
    sigv[kk] = 1e-6 + ((sp + 1e-6) * 65536.0) * 0.2;          // EPSILON + sigma
    valv[kk] = p2;
  }

  int pts[NPT];
#pragma unroll
  for (int kk = 0; kk < 4; ++kk) {
    const float m = m32[kk];
    pts[kk * 6 + 0] = (int)floorf(m);     // f32 boundaries on the f32 ref mean
    pts[kk * 6 + 1] = (int)ceilf(m);
    const float mr = rintf(m);            // jnp.round: half-to-even, f32
    float lowf = __fadd_rn(mr, -64.0f);
    if (lowf < 0.0f) lowf = 0.0f;
    if (__fadd_rn(mr, 64.0f) > 65536.0f) lowf = 65536.0f - 128.0f;
    const uint32_t base = (uint32_t)(row * 4 + kk) * 2u;
#pragma unroll
    for (int r2 = 0; r2 < 2; ++r2) {
      // rr_ints = floor((u*c1)*128 + lower), all f32.
      // (t*128 is exact pow2 scaling -> fma vs mul+add identical; rounding only at u*c1 and +lower)
      const float u = jax_u01f(kr0, kr1, base + (uint32_t)r2);
      const float t = __fmul_rn(u, c1f);
      pts[kk * 6 + 2 + r2] = (int)floorf(__fadd_rn(__fmul_rn(t, 128.0f), lowf));
    }
#pragma unroll
    for (int r2 = 0; r2 < 2; ++r2) {
      // g_ints = floor((u*c1)*65536), all f32 (pow2 scaling exact)
      const float u = jax_u01f(kg0, kg1, base + (uint32_t)r2);
      const float t = __fmul_rn(u, c1f);
      pts[kk * 6 + 4 + r2] = (int)floorf(__fmul_rn(t, 65536.0f));
    }
  }

  // dup[j] = exists j' < j with pts[j'] == pts[j] (stable argsort round-trip)
  uint32_t dup = 0u;
#pragma unroll
  for (int j = 1; j < NPT; ++j) {
    const int pj = pts[j];
    bool d = false;
#pragma unroll
    for (int j2 = 0; j2 < NPT - 1; ++j2) {
      if (j2 < j) d = d || (pts[j2] == pj);
    }
    if (d) dup |= (1u << j);
  }

  // pass 1: per-k normalization sums over non-dup points (f64, smooth)
  double S[4] = {0.0, 0.0, 0.0, 0.0};
#pragma unroll
  for (int j = 0; j < NPT; ++j) {
    if ((dup >> j) & 1u) continue;
#pragma unroll
    for (int kk = 0; kk < 4; ++kk) {
      const double d = (double)pts[j] - means[kk];
      S[kk] += gexp(0.5 * d * d / sigv[kk]);
    }
  }
  double t[4];
#pragma unroll
  for (int kk = 0; kk < 4; ++kk) t[kk] = valv[kk] / S[kk];

  // pass 2: weights, self-mask, emit (f32 store: 1e-7 rel << threshold)
  int* cb = tab + (size_t)row * 48;
  float* wb = (float*)(cb + 24);
#pragma unroll
  for (int j = 0; j < NPT; ++j) {
    double w = 0.0;
    if (!((dup >> j) & 1u)) {
      double acc = 0.0;
#pragma unroll
      for (int kk = 0; kk < 4; ++kk) {
        const double d = (double)pts[j] - means[kk];
        acc += gexp(0.5 * d * d / sigv[kk]) * t[kk];
      }
      w = acc;
    }
    if (pts[j] == row) w = 0.0;  // rows == cols mask
    cb[j] = pts[j];
    wb[j] = (float)w;
  }
}

// ---------------- Kernel B: gather-weighted sum, f32 output ----------------
__global__ void __launch_bounds__(256) gkern(const float4* __restrict__ x4,
                                             const int* __restrict__ tab,
                                             float4* __restrict__ out4) {
  __shared__ int sws[8 * 48];
  const int tid = threadIdx.x;
  const int rb = blockIdx.x * 8;
  {
    const int* src = tab + (size_t)rb * 48;
#pragma unroll
    for (int t = tid; t < 8 * 48; t += 256) sws[t] = src[t];
  }
  __syncthreads();

  const int sub = tid >> 5;
  const int lane = tid & 31;
  const int* cb = sws + sub * 48;
  const float* wb = (const float*)(cb + 24);

  float4 acc = make_float4(0.f, 0.f, 0.f, 0.f);
#pragma unroll
  for (int j = 0; j < NPT; ++j) {
    const float w = wb[j];
    if (fabsf(w) > 1e-6f) {  // dups/self/underflowed carry (near-)zero weight
      int c = cb[j];
      if (c > 65535) c = 65535;  // f32 rr path can round up to 65536; JAX gather clamps
      const float4 xv = x4[(size_t)c * 32 + lane];
      acc.x = fmaf(w, xv.x, acc.x);
      acc.y = fmaf(w, xv.y, acc.y);
      acc.z = fmaf(w, xv.z, acc.z);
      acc.w = fmaf(w, xv.w, acc.w);
    }
  }
  out4[(size_t)(rb + sub) * 32 + lane] = acc;
}

extern "C" void kernel_launch(void* const* d_in, const int* in_sizes, int n_in,
                              void* d_out, int out_size, void* d_ws, size_t ws_size,
                              hipStream_t stream) {
  const float* params = (const float*)d_in[0];
  const float* x = (const float*)d_in[1];
  if (n_in >= 2 && in_sizes[0] > in_sizes[1]) {  // order guard
    const float* tmp = params; params = x; x = tmp;
  }
  int* d_tab = (int*)d_ws;

  // split(jax.random.key(42)), partitionable/foldlike: key_i = block(key, (0, i))
  uint32_t kr0, kr1, kg0, kg1;
  { uint32_t a0 = 0u, a1 = 0u; tf2x32(0u, 42u, a0, a1); kr0 = a0; kr1 = a1; }
  { uint32_t b0 = 0u, b1 = 1u; tf2x32(0u, 42u, b0, b1); kg0 = b0; kg1 = b1; }

  hipLaunchKernelGGL(wkern, dim3(C_NUM / 256), dim3(256), 0, stream,
                     params, d_tab, kr0, kr1, kg0, kg1);
  hipLaunchKernelGGL(gkern, dim3(C_NUM / 8), dim3(256), 0, stream,
                     (const float4*)x, d_tab, (float4*)d_out);
}

// Round 2
// 161.408 us; speedup vs baseline: 1.2159x; 1.2159x over previous
//
#include <hip/hip_runtime.h>
#include <stdint.h>
#include <math.h>

#define C_NUM 65536
#define NPT 24

static __host__ __device__ __forceinline__ void tf2x32(uint32_t k0, uint32_t k1,
                                                       uint32_t& x0, uint32_t& x1) {
  const uint32_t ks2 = k0 ^ k1 ^ 0x1BD11BDAu;
#define TF_R(r) { x0 += x1; x1 = (x1 << (r)) | (x1 >> (32 - (r))); x1 ^= x0; }
  x0 += k0; x1 += k1;
  TF_R(13) TF_R(15) TF_R(26) TF_R(6)
  x0 += k1;  x1 += ks2 + 1u;
  TF_R(17) TF_R(29) TF_R(16) TF_R(24)
  x0 += ks2; x1 += k0 + 2u;
  TF_R(13) TF_R(15) TF_R(26) TF_R(6)
  x0 += k0;  x1 += k1 + 3u;
  TF_R(17) TF_R(29) TF_R(16) TF_R(24)
  x0 += k1;  x1 += ks2 + 4u;
  TF_R(13) TF_R(15) TF_R(26) TF_R(6)
  x0 += ks2; x1 += k0 + 5u;
#undef TF_R
}

// f32 uniform [0,1): x64-OFF partitionable path (jax _threefry_random_bits_partitionable):
//   counters (hi=0, lo=idx); bits32 = out0 ^ out1; u = bitcast((bits>>9)|0x3f800000) - 1.0f
// VALIDATED R1 (passed, absmax 0.0156) — do not touch.
__device__ __forceinline__ float jax_u01f(uint32_t ka, uint32_t kb, uint32_t idx) {
  uint32_t x0 = 0u, x1 = idx;
  tf2x32(ka, kb, x0, x1);
  const uint32_t bits = x0 ^ x1;
  return __fadd_rn(__uint_as_float((bits >> 9) | 0x3f800000u), -1.0f);
}

// XLA:CPU llvm_ir_runtime GenerateVF32Exp, bitwise replica. VALIDATED — discrete
// decisions (floor/ceil/round of means) depend on exact bits. Do not touch.
__device__ __forceinline__ float xla_vf32_exp(float x) {
  float xc = fminf(x, 88.3762626647950f);     // exp_hi
  xc = fmaxf(xc, -87.3365478515625f);         // exp_lo
  const float fx = floorf(fmaf(xc, 1.44269504088896341f, 0.5f));
  float r = fmaf(fx, -0.693359375f, xc);      // cephes_exp_C1
  r = fmaf(fx, 2.12194440e-4f, r);            // -C2
  const float z = __fmul_rn(r, r);
  float y = 1.9875691500e-4f;                 // p0
  y = fmaf(y, r, 1.3981999507e-3f);           // p1
  y = fmaf(y, r, 8.3334519073e-3f);           // p2
  y = fmaf(y, r, 4.1665795894e-2f);           // p3
  y = fmaf(y, r, 1.6666665459e-1f);           // p4
  y = fmaf(y, r, 5.0000001201e-1f);           // p5
  y = fmaf(y, z, r);
  y = __fadd_rn(y, 1.0f);
  const int n = (int)fx;                      // our inputs: |fx| <= ~9, exact scale
  return __fmul_rn(y, __uint_as_float((uint32_t)(127 + n) << 23));
}

// ---------------- Kernel A: per-row cols + weights -> table ----------------
// Discrete path (means replica, threefry ints, dup/self masks): unchanged from R1.
// Smooth path (Gaussian weights): now f32 like the reference — exp2f hardware
// transcendental with precomputed c2[k] = -0.5*log2(e)/sigma (no per-point divide).
__global__ void __launch_bounds__(256) wkern(const float* __restrict__ params,
                                             int* __restrict__ tab,
                                             uint32_t kr0, uint32_t kr1,
                                             uint32_t kg0, uint32_t kg1) {
  const int row = blockIdx.x * 256 + threadIdx.x;
  if (row >= C_NUM) return;

  const float c1f = (float)(1.0 - 1e-6);  // f32(1.0 - EPSILON)

  float m32[4], c2[4], valf[4];
#pragma unroll
  for (int kk = 0; kk < 4; ++kk) {
    const int r = row * 4 + kk;
    const float p0 = params[r * 3 + 0];
    const double p1 = (double)params[r * 3 + 1];
    // XLA logistic (exp-form): s = 1/(1 + exp(-x)); means = s * 65535  (all f32)
    const float e32 = xla_vf32_exp(-p0);
    const float s32 = __fdiv_rn(1.0f, __fadd_rn(1.0f, e32));
    m32[kk] = __fmul_rn(s32, 65535.0f);
    const double xx = p1 + 2.0;
    const double sp = fmax(xx, 0.0) + log1p(exp(-fabs(xx)));  // softplus (4/row: keep f64)
    const float sig = (float)(1e-6 + ((sp + 1e-6) * 65536.0) * 0.2);  // EPSILON + sigma
    c2[kk] = -0.72134752044448170f / sig;  // -0.5*log2(e)/sig; e = exp2(d^2 * c2)
    valf[kk] = params[r * 3 + 2];
  }

  int pts[NPT];
#pragma unroll
  for (int kk = 0; kk < 4; ++kk) {
    const float m = m32[kk];
    pts[kk * 6 + 0] = (int)floorf(m);     // f32 boundaries on the f32 ref mean
    pts[kk * 6 + 1] = (int)ceilf(m);
    const float mr = rintf(m);            // jnp.round: half-to-even, f32
    float lowf = __fadd_rn(mr, -64.0f);
    if (lowf < 0.0f) lowf = 0.0f;
    if (__fadd_rn(mr, 64.0f) > 65536.0f) lowf = 65536.0f - 128.0f;
    const uint32_t base = (uint32_t)(row * 4 + kk) * 2u;
#pragma unroll
    for (int r2 = 0; r2 < 2; ++r2) {
      // rr_ints = floor((u*c1)*128 + lower), all f32 (pow2 scaling exact)
      const float u = jax_u01f(kr0, kr1, base + (uint32_t)r2);
      const float t = __fmul_rn(u, c1f);
      pts[kk * 6 + 2 + r2] = (int)floorf(__fadd_rn(__fmul_rn(t, 128.0f), lowf));
    }
#pragma unroll
    for (int r2 = 0; r2 < 2; ++r2) {
      // g_ints = floor((u*c1)*65536), all f32 (pow2 scaling exact)
      const float u = jax_u01f(kg0, kg1, base + (uint32_t)r2);
      const float t = __fmul_rn(u, c1f);
      pts[kk * 6 + 4 + r2] = (int)floorf(__fmul_rn(t, 65536.0f));
    }
  }

  // dup[j] = exists j' < j with pts[j'] == pts[j] (stable argsort round-trip)
  uint32_t dup = 0u;
#pragma unroll
  for (int j = 1; j < NPT; ++j) {
    const int pj = pts[j];
    bool d = false;
#pragma unroll
    for (int j2 = 0; j2 < NPT - 1; ++j2) {
      if (j2 < j) d = d || (pts[j2] == pj);
    }
    if (d) dup |= (1u << j);
  }

  // pass 1: per-k normalization sums over non-dup points (f32, one exp2 per term)
  float S[4] = {0.f, 0.f, 0.f, 0.f};
#pragma unroll
  for (int j = 0; j < NPT; ++j) {
    const float live = ((dup >> j) & 1u) ? 0.0f : 1.0f;
    const float pf = (float)pts[j];
#pragma unroll
    for (int kk = 0; kk < 4; ++kk) {
      const float d = pf - m32[kk];
      S[kk] += live * exp2f(d * d * c2[kk]);  // huge-negative arg -> 0, no guard needed
    }
  }
  float t[4];
#pragma unroll
  for (int kk = 0; kk < 4; ++kk) t[kk] = __fdiv_rn(valf[kk], S[kk]);

  // pass 2: weights, dup/self mask, emit
  int* cb = tab + (size_t)row * 48;
  float* wb = (float*)(cb + 24);
#pragma unroll
  for (int j = 0; j < NPT; ++j) {
    const float pf = (float)pts[j];
    float acc = 0.f;
#pragma unroll
    for (int kk = 0; kk < 4; ++kk) {
      const float d = pf - m32[kk];
      acc = fmaf(exp2f(d * d * c2[kk]), t[kk], acc);
    }
    float w = ((dup >> j) & 1u) ? 0.f : acc;
    if (pts[j] == row) w = 0.f;  // rows == cols mask
    cb[j] = pts[j];
    wb[j] = w;
  }
}

// ---------------- Kernel B: gather-weighted sum, f32 output ----------------
// Branchless: dead entries (dup/self/underflow) redirect to column 0 (L1-hot)
// with w=0; loads chunked 8-deep so 8 gathers are in flight per wave.
__global__ void __launch_bounds__(256) gkern(const float4* __restrict__ x4,
                                             const int* __restrict__ tab,
                                             float4* __restrict__ out4) {
  __shared__ int sws[8 * 48];
  const int tid = threadIdx.x;
  const int rb = blockIdx.x * 8;
  {
    const int* src = tab + (size_t)rb * 48;
#pragma unroll
    for (int t = tid; t < 8 * 48; t += 256) sws[t] = src[t];
  }
  __syncthreads();

  const int sub = tid >> 5;
  const int lane = tid & 31;
  const int* cb = sws + sub * 48;
  const float* wb = (const float*)(cb + 24);

  float4 acc = make_float4(0.f, 0.f, 0.f, 0.f);
#pragma unroll
  for (int jc = 0; jc < NPT; jc += 8) {
    float wl[8];
    float4 xv[8];
#pragma unroll
    for (int u = 0; u < 8; ++u) {
      float w = wb[jc + u];
      int c = cb[jc + u];
      const bool live = fabsf(w) > 1e-6f;  // contribution < 1e-6*|x|: negligible
      wl[u] = live ? w : 0.0f;
      c = c > 65535 ? 65535 : c;           // f32 rr path can round to 65536; JAX clamps
      const int ce = live ? c : 0;         // dead -> hot line, ~free
      xv[u] = x4[(size_t)ce * 32 + lane];
    }
#pragma unroll
    for (int u = 0; u < 8; ++u) {
      acc.x = fmaf(wl[u], xv[u].x, acc.x);
      acc.y = fmaf(wl[u], xv[u].y, acc.y);
      acc.z = fmaf(wl[u], xv[u].z, acc.z);
      acc.w = fmaf(wl[u], xv[u].w, acc.w);
    }
  }
  out4[(size_t)(rb + sub) * 32 + lane] = acc;
}

extern "C" void kernel_launch(void* const* d_in, const int* in_sizes, int n_in,
                              void* d_out, int out_size, void* d_ws, size_t ws_size,
                              hipStream_t stream) {
  const float* params = (const float*)d_in[0];
  const float* x = (const float*)d_in[1];
  if (n_in >= 2 && in_sizes[0] > in_sizes[1]) {  // order guard
    const float* tmp = params; params = x; x = tmp;
  }
  int* d_tab = (int*)d_ws;

  // split(jax.random.key(42)), partitionable/foldlike: key_i = block(key, (0, i))
  uint32_t kr0, kr1, kg0, kg1;
  { uint32_t a0 = 0u, a1 = 0u; tf2x32(0u, 42u, a0, a1); kr0 = a0; kr1 = a1; }
  { uint32_t b0 = 0u, b1 = 1u; tf2x32(0u, 42u, b0, b1); kg0 = b0; kg1 = b1; }

  hipLaunchKernelGGL(wkern, dim3(C_NUM / 256), dim3(256), 0, stream,
                     params, d_tab, kr0, kr1, kg0, kg1);
  hipLaunchKernelGGL(gkern, dim3(C_NUM / 8), dim3(256), 0, stream,
                     (const float4*)x, d_tab, (float4*)d_out);
}

// Round 4
// 159.935 us; speedup vs baseline: 1.2271x; 1.0092x over previous
//
#include <hip/hip_runtime.h>
#include <stdint.h>
#include <math.h>

#define C_NUM 65536
#define NPT 24

typedef float nfloat4 __attribute__((ext_vector_type(4)));  // native vec for nontemporal builtin

static __host__ __device__ __forceinline__ void tf2x32(uint32_t k0, uint32_t k1,
                                                       uint32_t& x0, uint32_t& x1) {
  const uint32_t ks2 = k0 ^ k1 ^ 0x1BD11BDAu;
#define TF_R(r) { x0 += x1; x1 = (x1 << (r)) | (x1 >> (32 - (r))); x1 ^= x0; }
  x0 += k0; x1 += k1;
  TF_R(13) TF_R(15) TF_R(26) TF_R(6)
  x0 += k1;  x1 += ks2 + 1u;
  TF_R(17) TF_R(29) TF_R(16) TF_R(24)
  x0 += ks2; x1 += k0 + 2u;
  TF_R(13) TF_R(15) TF_R(26) TF_R(6)
  x0 += k0;  x1 += k1 + 3u;
  TF_R(17) TF_R(29) TF_R(16) TF_R(24)
  x0 += k1;  x1 += ks2 + 4u;
  TF_R(13) TF_R(15) TF_R(26) TF_R(6)
  x0 += ks2; x1 += k0 + 5u;
#undef TF_R
}

// f32 uniform [0,1): x64-OFF partitionable path. VALIDATED R1/R2 — do not touch.
__device__ __forceinline__ float jax_u01f(uint32_t ka, uint32_t kb, uint32_t idx) {
  uint32_t x0 = 0u, x1 = idx;
  tf2x32(ka, kb, x0, x1);
  const uint32_t bits = x0 ^ x1;
  return __fadd_rn(__uint_as_float((bits >> 9) | 0x3f800000u), -1.0f);
}

// XLA:CPU GenerateVF32Exp bitwise replica. VALIDATED — discrete decisions depend
// on exact bits. Do not touch.
__device__ __forceinline__ float xla_vf32_exp(float x) {
  float xc = fminf(x, 88.3762626647950f);     // exp_hi
  xc = fmaxf(xc, -87.3365478515625f);         // exp_lo
  const float fx = floorf(fmaf(xc, 1.44269504088896341f, 0.5f));
  float r = fmaf(fx, -0.693359375f, xc);      // cephes_exp_C1
  r = fmaf(fx, 2.12194440e-4f, r);            // -C2
  const float z = __fmul_rn(r, r);
  float y = 1.9875691500e-4f;                 // p0
  y = fmaf(y, r, 1.3981999507e-3f);           // p1
  y = fmaf(y, r, 8.3334519073e-3f);           // p2
  y = fmaf(y, r, 4.1665795894e-2f);           // p3
  y = fmaf(y, r, 1.6666665459e-1f);           // p4
  y = fmaf(y, r, 5.0000001201e-1f);           // p5
  y = fmaf(y, z, r);
  y = __fadd_rn(y, 1.0f);
  const int n = (int)fx;                      // our inputs: |fx| <= ~9, exact scale
  return __fmul_rn(y, __uint_as_float((uint32_t)(127 + n) << 23));
}

// ---------------- Kernel A: one thread per (row,k) ----------------
// R2 post-mortem: per-row layout ran 1 wave/SIMD with pts[24]+all-pairs state
// (scratch-spill candidate, no latency hiding). Now 262144 threads (4 waves/SIMD),
// per-thread: 4 threefry, 6 pts, 1 softplus, 48 exp2. Cross-k (dup mask, t[])
// exchanged via LDS. Discrete math bit-identical to the validated R2 path.
__global__ void __launch_bounds__(256) wkern(const float* __restrict__ params,
                                             int* __restrict__ tab,
                                             uint32_t kr0, uint32_t kr1,
                                             uint32_t kg0, uint32_t kg1) {
  const int g    = blockIdx.x * 256 + threadIdx.x;  // == row*4 + kk
  const int row  = g >> 2;
  const int kk   = g & 3;
  const int lrow = threadIdx.x >> 2;                // row-in-block, 0..63

  __shared__ int   s_pts[64][25];   // +1 pad: 16 lrows/wave -> conflict-light
  __shared__ float s_m[64][4];
  __shared__ float s_c2[64][4];
  __shared__ float s_t[64][4];

  // --- per-(row,k) params (12B contiguous per thread) ---
  const float p0  = params[g * 3 + 0];
  const float p1f = params[g * 3 + 1];
  const float p2  = params[g * 3 + 2];

  // XLA logistic (exp-form): s = 1/(1+exp(-x)); mean = s*65535 (all f32)
  const float e32 = xla_vf32_exp(-p0);
  const float s32 = __fdiv_rn(1.0f, __fadd_rn(1.0f, e32));
  const float m   = __fmul_rn(s32, 65535.0f);

  const double xx = (double)p1f + 2.0;
  const double sp = fmax(xx, 0.0) + log1p(exp(-fabs(xx)));  // softplus (1/thread: keep f64)
  const float sig = (float)(1e-6 + ((sp + 1e-6) * 65536.0) * 0.2);
  const float c2  = -0.72134752044448170f / sig;  // -0.5*log2(e)/sig

  // --- 6 sample points (bit-identical to R2) ---
  const float c1f = (float)(1.0 - 1e-6);
  int pt[6];
  pt[0] = (int)floorf(m);
  pt[1] = (int)ceilf(m);
  const float mr = rintf(m);                      // jnp.round: half-to-even
  float lowf = __fadd_rn(mr, -64.0f);
  if (lowf < 0.0f) lowf = 0.0f;
  if (__fadd_rn(mr, 64.0f) > 65536.0f) lowf = 65536.0f - 128.0f;
  const uint32_t base = (uint32_t)g * 2u;
#pragma unroll
  for (int r2 = 0; r2 < 2; ++r2) {
    const float u = jax_u01f(kr0, kr1, base + (uint32_t)r2);
    const float t = __fmul_rn(u, c1f);
    pt[2 + r2] = (int)floorf(__fadd_rn(__fmul_rn(t, 128.0f), lowf));
  }
#pragma unroll
  for (int r2 = 0; r2 < 2; ++r2) {
    const float u = jax_u01f(kg0, kg1, base + (uint32_t)r2);
    const float t = __fmul_rn(u, c1f);
    pt[4 + r2] = (int)floorf(__fmul_rn(t, 65536.0f));
  }

#pragma unroll
  for (int jj = 0; jj < 6; ++jj) s_pts[lrow][kk * 6 + jj] = pt[jj];
  s_m[lrow][kk]  = m;
  s_c2[lrow][kk] = c2;
  __syncthreads();

  // row's 24 points into registers
  int p24[NPT];
#pragma unroll
  for (int j = 0; j < NPT; ++j) p24[j] = s_pts[lrow][j];

  // dup[j] = exists j' < j with p24[j'] == p24[j] (same comparisons/order as R2)
  uint32_t dup = 0u;
#pragma unroll
  for (int j = 1; j < NPT; ++j) {
    const int pj = p24[j];
    bool d = false;
#pragma unroll
    for (int j2 = 0; j2 < NPT - 1; ++j2) {
      if (j2 < j) d = d || (p24[j2] == pj);
    }
    if (d) dup |= (1u << j);
  }

  // normalization sum for my k (same j-order as R2's accumulation)
  float S = 0.f;
#pragma unroll
  for (int j = 0; j < NPT; ++j) {
    const float live = ((dup >> j) & 1u) ? 0.0f : 1.0f;
    const float d = (float)p24[j] - m;
    S += live * exp2f(d * d * c2);   // huge-negative arg -> 0, no guard needed
  }
  s_t[lrow][kk] = __fdiv_rn(p2, S);
  __syncthreads();

  float mv[4], c2v[4], tv[4];
#pragma unroll
  for (int q = 0; q < 4; ++q) {
    mv[q]  = s_m[lrow][q];
    c2v[q] = s_c2[lrow][q];
    tv[q]  = s_t[lrow][q];
  }

  // weights for my 6 points (same fmaf chain, kk order 0..3, as R2 pass 2)
  int* cb = tab + (size_t)row * 48;
  float* wb = (float*)(cb + 24);
#pragma unroll
  for (int jj = 0; jj < 6; ++jj) {
    const int j = kk * 6 + jj;
    const float pf = (float)pt[jj];
    float acc = 0.f;
#pragma unroll
    for (int q = 0; q < 4; ++q) {
      const float d = pf - mv[q];
      acc = fmaf(exp2f(d * d * c2v[q]), tv[q], acc);
    }
    float w = ((dup >> j) & 1u) ? 0.f : acc;
    if (pt[jj] == row) w = 0.f;  // rows == cols mask
    cb[j] = pt[jj];
    wb[j] = w;
  }
}

// ---------------- Kernel B: gather-weighted sum ----------------
// R1 branchy form (74.2 µs, VGPR 8) — R2's branchless 8-deep chunk was neutral
// (latency already TLP-hidden at 77% occupancy). New: nontemporal output store
// (via native ext_vector_type — HIP float4 class is rejected by the builtin)
// so the 32 MB out stream doesn't evict the 32 MB x working set from L2.
__global__ void __launch_bounds__(256) gkern(const float4* __restrict__ x4,
                                             const int* __restrict__ tab,
                                             float4* __restrict__ out4) {
  __shared__ int sws[8 * 48];
  const int tid = threadIdx.x;
  const int rb = blockIdx.x * 8;
  {
    const int* src = tab + (size_t)rb * 48;
#pragma unroll
    for (int t = tid; t < 8 * 48; t += 256) sws[t] = src[t];
  }
  __syncthreads();

  const int sub = tid >> 5;
  const int lane = tid & 31;
  const int* cb = sws + sub * 48;
  const float* wb = (const float*)(cb + 24);

  float4 acc = make_float4(0.f, 0.f, 0.f, 0.f);
#pragma unroll
  for (int j = 0; j < NPT; ++j) {
    const float w = wb[j];
    if (fabsf(w) > 1e-6f) {  // dups/self/underflowed carry (near-)zero weight
      int c = cb[j];
      if (c > 65535) c = 65535;  // f32 rr path can round up to 65536; JAX clamps
      const float4 xv = x4[(size_t)c * 32 + lane];
      acc.x = fmaf(w, xv.x, acc.x);
      acc.y = fmaf(w, xv.y, acc.y);
      acc.z = fmaf(w, xv.z, acc.z);
      acc.w = fmaf(w, xv.w, acc.w);
    }
  }
  nfloat4 av; av.x = acc.x; av.y = acc.y; av.z = acc.z; av.w = acc.w;
  __builtin_nontemporal_store(av, (nfloat4*)(out4 + (size_t)(rb + sub) * 32 + lane));
}

extern "C" void kernel_launch(void* const* d_in, const int* in_sizes, int n_in,
                              void* d_out, int out_size, void* d_ws, size_t ws_size,
                              hipStream_t stream) {
  const float* params = (const float*)d_in[0];
  const float* x = (const float*)d_in[1];
  if (n_in >= 2 && in_sizes[0] > in_sizes[1]) {  // order guard
    const float* tmp = params; params = x; x = tmp;
  }
  int* d_tab = (int*)d_ws;

  // split(jax.random.key(42)), partitionable/foldlike: key_i = block(key, (0, i))
  uint32_t kr0, kr1, kg0, kg1;
  { uint32_t a0 = 0u, a1 = 0u; tf2x32(0u, 42u, a0, a1); kr0 = a0; kr1 = a1; }
  { uint32_t b0 = 0u, b1 = 1u; tf2x32(0u, 42u, b0, b1); kg0 = b0; kg1 = b1; }

  hipLaunchKernelGGL(wkern, dim3((C_NUM * 4) / 256), dim3(256), 0, stream,
                     params, d_tab, kr0, kr1, kg0, kg1);
  hipLaunchKernelGGL(gkern, dim3(C_NUM / 8), dim3(256), 0, stream,
                     (const float4*)x, d_tab, (float4*)d_out);
}